// Round 7
// baseline (158.992 us; speedup 1.0000x reference)
//
#include <hip/hip_runtime.h>
#include <hip/hip_bf16.h>

// Output row i (N = P*4 rows, D = 256 f32 each):
//   p = mapping[i]
//   last-of-group  <=> i == N-1 || mapping[i+1] != p
//   last  -> solvent_features[p]
//   else  -> monomer_features[i - p]   // monomer rank = i - (#lasts before i) = i - p
// Pure memory-bound gather (821 MB traffic, roofline ~130 us @ 6.3 TB/s).
// R7: R4 structure (4 adjacent rows per wave-iter, lane-broadcast mapping
// loads) with ALL nontemporal hints removed — isolates the NT variable.

typedef float f32x4 __attribute__((ext_vector_type(4)));

__global__ void __launch_bounds__(256)
separated_gnn_gather(const f32x4* __restrict__ mono,    // [P*3 * 64]
                     const f32x4* __restrict__ solv,    // [P   * 64]
                     const int*   __restrict__ mapping, // [N]
                     f32x4*       __restrict__ out,     // [N * 64]
                     int n_rows)
{
    const int lane    = threadIdx.x & 63;
    const long long wave    = ((long long)blockIdx.x * blockDim.x + threadIdx.x) >> 6;
    const long long n_waves = ((long long)gridDim.x * blockDim.x) >> 6;

    const int n_chunks = n_rows >> 2;          // 4 adjacent rows per wave-iter

    for (long long g = wave; g < n_chunks; g += n_waves) {
        const int base = (int)(g << 2);        // first row of chunk

        // Mapping words for rows base..base+4 (5 values, issued together).
        int m[5];
#pragma unroll
        for (int k = 0; k < 5; ++k) {
            const int idx = base + k;
            m[k] = (idx < n_rows) ? mapping[idx] : -1;   // -1 forces "last" at array end
        }

        // Per-row source addresses (general per-row logic; chunking is layout only).
        const f32x4* src[4];
#pragma unroll
        for (int k = 0; k < 4; ++k) {
            const int i = base + k;
            const int p = m[k];
            const bool last = (m[k + 1] != p);
            src[k] = last ? (solv + (long long)p * 64)
                          : (mono + (long long)(i - p) * 64);
        }

        // 4 independent 1KB loads (plain cached loads — NT removed).
        f32x4 v0 = src[0][lane];
        f32x4 v1 = src[1][lane];
        f32x4 v2 = src[2][lane];
        f32x4 v3 = src[3][lane];

        // 4KB contiguous store (plain cached stores — NT removed).
        f32x4* o = out + (long long)base * 64 + lane;
        o[0]   = v0;
        o[64]  = v1;
        o[128] = v2;
        o[192] = v3;
    }

    // Generic tail for n_rows % 4 != 0 (empty for N = 400000).
    const long long tail_start = (long long)n_chunks * 4 * 64;
    const long long total      = (long long)n_rows * 64;
    const long long stride     = (long long)gridDim.x * blockDim.x;
    for (long long t = tail_start + (long long)blockIdx.x * blockDim.x + threadIdx.x;
         t < total; t += stride) {
        const int i = (int)(t >> 6);
        const int c = (int)(t & 63);
        const int p = mapping[i];
        const bool last = (i + 1 == n_rows) || (mapping[i + 1] != p);
        const f32x4* s = last ? (solv + (long long)p * 64)
                              : (mono + (long long)(i - p) * 64);
        out[t] = s[c];
    }
}

extern "C" void kernel_launch(void* const* d_in, const int* in_sizes, int n_in,
                              void* d_out, int out_size, void* d_ws, size_t ws_size,
                              hipStream_t stream)
{
    const f32x4* mono    = (const f32x4*)d_in[0];   // monomer_features  [P*3, 256] f32
    const f32x4* solv    = (const f32x4*)d_in[1];   // solvent_features  [P,   256] f32
    const int*   mapping = (const int*)d_in[2];     // polymer_mapping   [N] int32
    f32x4*       out     = (f32x4*)d_out;           // [N, 256] f32

    const int n_rows = in_sizes[2];                 // N = 400000

    const int block = 256;
    const int grid  = 2048;                         // 8192 waves, grid-stride chunks

    separated_gnn_gather<<<grid, block, 0, stream>>>(mono, solv, mapping, out, n_rows);
}

// Round 8
// 144.450 us; speedup vs baseline: 1.1007x; 1.1007x over previous
//
#include <hip/hip_runtime.h>
#include <hip/hip_bf16.h>

// Output row i (N = P*4 rows, D = 256 f32 each):
//   p = mapping[i]
//   last-of-group  <=> i == N-1 || mapping[i+1] != p
//   last  -> solvent_features[p]
//   else  -> monomer_features[i - p]   // monomer rank = i - (#lasts before i) = i - p
// Pure memory-bound gather (821 MB traffic, roofline ~130 us @ 6.3 TB/s).
// FINAL (== R4, the best measured config, 144.2 us = 90.5% of copy ceiling):
//   - 4 adjacent rows per wave-iter: 4KB contiguous store, ~3KB contiguous
//     mono read + 1KB solv read per iteration (granularity was +6%)
//   - lane-broadcast vector mapping loads (scalarized s_load variant was -2%)
//   - nontemporal load/store hints on all 820 MB of single-pass data (+10%)
// Isolated-variable ledger: MLP unroll null (R2), chunk 8 neutral (R6),
// readfirstlane -2% (R5), no-NT -10% (R7).

typedef float f32x4 __attribute__((ext_vector_type(4)));

__global__ void __launch_bounds__(256)
separated_gnn_gather(const f32x4* __restrict__ mono,    // [P*3 * 64]
                     const f32x4* __restrict__ solv,    // [P   * 64]
                     const int*   __restrict__ mapping, // [N]
                     f32x4*       __restrict__ out,     // [N * 64]
                     int n_rows)
{
    const int lane    = threadIdx.x & 63;
    const long long wave    = ((long long)blockIdx.x * blockDim.x + threadIdx.x) >> 6;
    const long long n_waves = ((long long)gridDim.x * blockDim.x) >> 6;

    const int n_chunks = n_rows >> 2;          // 4 adjacent rows per wave-iter

    for (long long g = wave; g < n_chunks; g += n_waves) {
        const int base = (int)(g << 2);        // first row of chunk

        // Mapping words for rows base..base+4 (5 values, issued together).
        int m[5];
#pragma unroll
        for (int k = 0; k < 5; ++k) {
            const int idx = base + k;
            m[k] = (idx < n_rows) ? mapping[idx] : -1;   // -1 forces "last" at array end
        }

        // Per-row source addresses (general per-row logic; chunking is layout only).
        const f32x4* src[4];
#pragma unroll
        for (int k = 0; k < 4; ++k) {
            const int i = base + k;
            const int p = m[k];
            const bool last = (m[k + 1] != p);
            src[k] = last ? (solv + (long long)p * 64)
                          : (mono + (long long)(i - p) * 64);
        }

        // 4 independent 1KB loads (mono rows contiguous -> wave spans ~3KB+1KB).
        f32x4 v0 = __builtin_nontemporal_load(src[0] + lane);
        f32x4 v1 = __builtin_nontemporal_load(src[1] + lane);
        f32x4 v2 = __builtin_nontemporal_load(src[2] + lane);
        f32x4 v3 = __builtin_nontemporal_load(src[3] + lane);

        // 4KB contiguous store.
        f32x4* o = out + (long long)base * 64 + lane;
        __builtin_nontemporal_store(v0, o);
        __builtin_nontemporal_store(v1, o + 64);
        __builtin_nontemporal_store(v2, o + 128);
        __builtin_nontemporal_store(v3, o + 192);
    }

    // Generic tail for n_rows % 4 != 0 (empty for N = 400000).
    const long long tail_start = (long long)n_chunks * 4 * 64;
    const long long total      = (long long)n_rows * 64;
    const long long stride     = (long long)gridDim.x * blockDim.x;
    for (long long t = tail_start + (long long)blockIdx.x * blockDim.x + threadIdx.x;
         t < total; t += stride) {
        const int i = (int)(t >> 6);
        const int c = (int)(t & 63);
        const int p = mapping[i];
        const bool last = (i + 1 == n_rows) || (mapping[i + 1] != p);
        const f32x4* s = last ? (solv + (long long)p * 64)
                              : (mono + (long long)(i - p) * 64);
        __builtin_nontemporal_store(__builtin_nontemporal_load(s + c), out + t);
    }
}

extern "C" void kernel_launch(void* const* d_in, const int* in_sizes, int n_in,
                              void* d_out, int out_size, void* d_ws, size_t ws_size,
                              hipStream_t stream)
{
    const f32x4* mono    = (const f32x4*)d_in[0];   // monomer_features  [P*3, 256] f32
    const f32x4* solv    = (const f32x4*)d_in[1];   // solvent_features  [P,   256] f32
    const int*   mapping = (const int*)d_in[2];     // polymer_mapping   [N] int32
    f32x4*       out     = (f32x4*)d_out;           // [N, 256] f32

    const int n_rows = in_sizes[2];                 // N = 400000

    const int block = 256;
    const int grid  = 2048;                         // 8192 waves, grid-stride chunks

    separated_gnn_gather<<<grid, block, 0, stream>>>(mono, solv, mapping, out, n_rows);
}